// Round 3
// baseline (364.035 us; speedup 1.0000x reference)
//
#include <hip/hip_runtime.h>
#include <hip/hip_bf16.h>

#define N_ROWS 8192
#define DIM    128
#define TWO_N  16384
#define CSPLIT 16
#define COLS_PER_BLOCK (TWO_N / CSPLIT)   // 1024
#define CT 64                             // cols per LDS tile
#define NT (COLS_PER_BLOCK / CT)          // 16 tiles
#define NBLOCKS ((TWO_N / 256) * CSPLIT)  // 64 x 16 = 1024
#define EXP_TWO 7.38905609893065f
// sqrt(2*log2(e)): H is pre-scaled by this, so dot(Hs_i,Hs_j) = 2*log2(e)*dot(h_i,h_j)
// and exp(2*dot) == exp2(scaled MFMA output) -- one v_exp_f32, zero extra v_mul.
#define SCALE_SQRT 1.6986430142593980f

typedef __attribute__((ext_vector_type(8))) short short8;
typedef __attribute__((ext_vector_type(4))) float float4v;

__device__ inline void async_copy16(const void* g, void* l) {
  __builtin_amdgcn_global_load_lds(
      (const __attribute__((address_space(1))) void*)g,
      (__attribute__((address_space(3))) void*)l, 16, 0, 0);
}

// ---------------------------------------------------------------------------
// Kernel 1: L2-normalize rows of h1,h2 (fp32), write bf16 H = sqrt(2log2e)*[h1n; h2n],
// exact fp32 pos-dot per row. Also zeroes rowsum + completion counter (replaces
// a memset dispatch; kernel boundary makes the zeros visible to ntx_main).
// One wave per row; block = 4 waves.
// ---------------------------------------------------------------------------
__global__ __launch_bounds__(256) void norm_kernel(
    const float* __restrict__ h1, const float* __restrict__ h2,
    __hip_bfloat16* __restrict__ Hb, float* __restrict__ posdot,
    float* __restrict__ rowsum, unsigned* __restrict__ counter) {
  int tid  = threadIdx.x;
  int lane = tid & 63;
  int w    = tid >> 6;
  int row  = blockIdx.x * 4 + w;                  // 0..8191

  // zero rowsum (16384 floats over 2048 blocks) + counter
  if (tid < 8) rowsum[blockIdx.x * 8 + tid] = 0.0f;
  if (blockIdx.x == 0 && tid == 8) *counter = 0u;

  const float2* p1 = (const float2*)(h1 + (size_t)row * DIM);
  const float2* p2 = (const float2*)(h2 + (size_t)row * DIM);
  float2 v1 = p1[lane];
  float2 v2 = p2[lane];

  float ss1 = v1.x * v1.x + v1.y * v1.y;
  float ss2 = v2.x * v2.x + v2.y * v2.y;
  #pragma unroll
  for (int m = 32; m; m >>= 1) {
    ss1 += __shfl_xor(ss1, m);
    ss2 += __shfl_xor(ss2, m);
  }
  float inv1 = 1.0f / fmaxf(sqrtf(ss1), 1e-12f);
  float inv2 = 1.0f / fmaxf(sqrtf(ss2), 1e-12f);

  float ax = v1.x * inv1, ay = v1.y * inv1;
  float bx = v2.x * inv2, by = v2.y * inv2;

  float pd = ax * bx + ay * by;   // exact (unscaled) positive-pair dot
  #pragma unroll
  for (int m = 32; m; m >>= 1) pd += __shfl_xor(pd, m);

  __hip_bfloat162* o1 = (__hip_bfloat162*)(Hb + (size_t)row * DIM);
  __hip_bfloat162* o2 = (__hip_bfloat162*)(Hb + (size_t)(row + N_ROWS) * DIM);
  __hip_bfloat162 t1, t2;
  t1.x = __float2bfloat16(ax * SCALE_SQRT); t1.y = __float2bfloat16(ay * SCALE_SQRT);
  t2.x = __float2bfloat16(bx * SCALE_SQRT); t2.y = __float2bfloat16(by * SCALE_SQRT);
  o1[lane] = t1;
  o2[lane] = t2;

  if (lane == 0) posdot[row] = pd;
}

// ---------------------------------------------------------------------------
// Kernel 2: row sums of exp2(Hs Hs^T) (== exp(2 H H^T)) without materializing.
// Block: 4 waves; each wave owns 64 rows (A fully register-resident, K=128).
// B tiles (64 cols x 128 k) staged via global_load_lds in MFMA fragment order
// so ds_read_b128 is lane-sequential (2-way alias = free).
// Grid (64 row-stripes, 16 col-splits) = 1024 blocks = 4 blocks/CU.
// Last-finishing block computes the final loss (completion-counter pattern).
// ---------------------------------------------------------------------------
__global__ __launch_bounds__(256, 4) void ntx_main(
    const __hip_bfloat16* __restrict__ Hb, float* __restrict__ rowsum,
    const float* __restrict__ posdot, unsigned* __restrict__ counter,
    float* __restrict__ out) {
  __shared__ short smem[1024 * 8];   // 16 KB: 1024 chunks of 16 B
  const short* H = (const short*)Hb;

  int tid  = threadIdx.x;
  int lane = tid & 63;
  int w    = tid >> 6;
  int q    = lane >> 4;     // k-chunk selector within fragment
  int m    = lane & 15;     // row/col within 16-subtile

  int rowbase = blockIdx.x * 256 + w * 64;
  int colbase = blockIdx.y * COLS_PER_BLOCK;

  // A fragments: 4 row-subtiles x 4 k-steps, resident for the whole kernel.
  short8 a[4][4];
  #pragma unroll
  for (int r = 0; r < 4; ++r)
    #pragma unroll
    for (int s = 0; s < 4; ++s)
      a[r][s] = *(const short8*)(H + (size_t)(rowbase + r * 16 + m) * DIM + s * 32 + q * 8);

  float rowacc[4][4];
  #pragma unroll
  for (int r = 0; r < 4; ++r)
    #pragma unroll
    for (int i = 0; i < 4; ++i) rowacc[r][i] = 0.0f;

  // staging address components (invariant across tiles)
  int s_l15 = tid & 15;            // B row within subtile
  int s_lq  = (tid >> 4) & 3;      // k chunk
  int s_s   = (tid >> 6) & 3;      // k step (== wave id)

  for (int ct = 0; ct < NT; ++ct) {
    int j0 = colbase + ct * CT;
    #pragma unroll
    for (int rr = 0; rr < 4; ++rr) {
      int i = rr * 256 + tid;      // chunk index 0..1023; c = rr
      const short* g = H + (size_t)(j0 + rr * 16 + s_l15) * DIM + s_s * 32 + s_lq * 8;
      async_copy16(g, (void*)&smem[i * 8]);
    }
    __syncthreads();

    #pragma unroll
    for (int c = 0; c < 4; ++c) {
      short8 b[4];
      #pragma unroll
      for (int s = 0; s < 4; ++s)
        b[s] = *(const short8*)&smem[(c * 256 + s * 64 + lane) * 8];
      #pragma unroll
      for (int r = 0; r < 4; ++r) {
        float4v acc = {0.f, 0.f, 0.f, 0.f};
        #pragma unroll
        for (int s = 0; s < 4; ++s)
          acc = __builtin_amdgcn_mfma_f32_16x16x32_bf16(a[r][s], b[s], acc, 0, 0, 0);
        #pragma unroll
        for (int i = 0; i < 4; ++i)
          rowacc[r][i] += __builtin_amdgcn_exp2f(acc[i]);
      }
    }
    __syncthreads();
  }

  // Reduce across the 16 column-lanes holding the same rows, then atomicAdd.
  #pragma unroll
  for (int r = 0; r < 4; ++r)
    #pragma unroll
    for (int i = 0; i < 4; ++i) {
      float v = rowacc[r][i];
      v += __shfl_xor(v, 1);
      v += __shfl_xor(v, 2);
      v += __shfl_xor(v, 4);
      v += __shfl_xor(v, 8);
      rowacc[r][i] = v;
    }
  if (m == 0) {
    #pragma unroll
    for (int r = 0; r < 4; ++r)
      #pragma unroll
      for (int i = 0; i < 4; ++i)
        atomicAdd(&rowsum[rowbase + r * 16 + q * 4 + i], rowacc[r][i]);
  }

  // ---- completion-counter finalize (last block computes the loss) ----
  __shared__ unsigned is_last;
  __threadfence();          // release our rowsum atomics
  __syncthreads();
  if (tid == 0) {
    unsigned old = atomicAdd(counter, 1u);
    is_last = (old == NBLOCKS - 1) ? 1u : 0u;
  }
  __syncthreads();
  if (is_last) {
    __threadfence();        // acquire all blocks' rowsum atomics
    float* smemf = (float*)smem;
    float ld = 0.0f, pp = 0.0f;
    for (int i = tid; i < TWO_N; i += 256) {
      float v = __hip_atomic_load(&rowsum[i], __ATOMIC_RELAXED, __HIP_MEMORY_SCOPE_AGENT);
      ld += __logf(v - EXP_TWO);
    }
    for (int i = tid; i < N_ROWS; i += 256) pp += posdot[i];
    #pragma unroll
    for (int mm = 32; mm; mm >>= 1) {
      ld += __shfl_xor(ld, mm);
      pp += __shfl_xor(pp, mm);
    }
    if (lane == 0) { smemf[w] = ld; smemf[4 + w] = pp; }
    __syncthreads();
    if (tid == 0) {
      float tl = smemf[0] + smemf[1] + smemf[2] + smemf[3];
      float tp = smemf[4] + smemf[5] + smemf[6] + smemf[7];
      *out = (tl - 4.0f * tp) / (float)TWO_N;
    }
  }
}

extern "C" void kernel_launch(void* const* d_in, const int* in_sizes, int n_in,
                              void* d_out, int out_size, void* d_ws, size_t ws_size,
                              hipStream_t stream) {
  const float* h1 = (const float*)d_in[0];
  const float* h2 = (const float*)d_in[1];
  char* ws = (char*)d_ws;

  __hip_bfloat16* Hb = (__hip_bfloat16*)ws;                       // 4 MB
  float* rowsum      = (float*)(ws + 4194304);                    // 64 KB
  float* posdot      = (float*)(ws + 4194304 + 65536);            // 32 KB
  unsigned* counter  = (unsigned*)(ws + 4194304 + 65536 + 32768); // 4 B
  float* out         = (float*)d_out;

  norm_kernel<<<N_ROWS / 4, 256, 0, stream>>>(h1, h2, Hb, posdot, rowsum, counter);
  ntx_main<<<dim3(TWO_N / 256, CSPLIT), 256, 0, stream>>>(Hb, rowsum, posdot, counter, out);
}

// Round 4
// 212.425 us; speedup vs baseline: 1.7137x; 1.7137x over previous
//
#include <hip/hip_runtime.h>
#include <hip/hip_bf16.h>

#define N_ROWS 8192
#define DIM    128
#define TWO_N  16384
#define CSPLIT 16
#define COLS_PER_BLOCK (TWO_N / CSPLIT)   // 1024
#define CT 64                             // cols per LDS tile
#define NT (COLS_PER_BLOCK / CT)          // 16 tiles
#define NBLOCKS ((TWO_N / 256) * CSPLIT)  // 64 x 16 = 1024
#define EXP_TWO 7.38905609893065f
// sqrt(2*log2(e)): H is pre-scaled by this, so dot(Hs_i,Hs_j) = 2*log2(e)*dot(h_i,h_j)
// and exp(2*dot) == exp2(scaled MFMA output) -- one v_exp_f32, zero extra v_mul.
#define SCALE_SQRT 1.6986430142593980f

typedef __attribute__((ext_vector_type(8))) short short8;
typedef __attribute__((ext_vector_type(4))) float float4v;

__device__ inline void async_copy16(const void* g, void* l) {
  __builtin_amdgcn_global_load_lds(
      (const __attribute__((address_space(1))) void*)g,
      (__attribute__((address_space(3))) void*)l, 16, 0, 0);
}

// ---------------------------------------------------------------------------
// Kernel 1: L2-normalize rows of h1,h2 (fp32), write bf16 H = sqrt(2log2e)*[h1n; h2n],
// exact fp32 pos-dot per row. Also zeroes rowsum + completion counter.
// One wave per row; block = 4 waves.
// ---------------------------------------------------------------------------
__global__ __launch_bounds__(256) void norm_kernel(
    const float* __restrict__ h1, const float* __restrict__ h2,
    __hip_bfloat16* __restrict__ Hb, float* __restrict__ posdot,
    float* __restrict__ rowsum, unsigned* __restrict__ counter) {
  int tid  = threadIdx.x;
  int lane = tid & 63;
  int w    = tid >> 6;
  int row  = blockIdx.x * 4 + w;                  // 0..8191

  // zero rowsum (16384 floats over 2048 blocks) + counter
  if (tid < 8) rowsum[blockIdx.x * 8 + tid] = 0.0f;
  if (blockIdx.x == 0 && tid == 8) *counter = 0u;

  const float2* p1 = (const float2*)(h1 + (size_t)row * DIM);
  const float2* p2 = (const float2*)(h2 + (size_t)row * DIM);
  float2 v1 = p1[lane];
  float2 v2 = p2[lane];

  float ss1 = v1.x * v1.x + v1.y * v1.y;
  float ss2 = v2.x * v2.x + v2.y * v2.y;
  #pragma unroll
  for (int m = 32; m; m >>= 1) {
    ss1 += __shfl_xor(ss1, m);
    ss2 += __shfl_xor(ss2, m);
  }
  float inv1 = 1.0f / fmaxf(sqrtf(ss1), 1e-12f);
  float inv2 = 1.0f / fmaxf(sqrtf(ss2), 1e-12f);

  float ax = v1.x * inv1, ay = v1.y * inv1;
  float bx = v2.x * inv2, by = v2.y * inv2;

  float pd = ax * bx + ay * by;   // exact (unscaled) positive-pair dot
  #pragma unroll
  for (int m = 32; m; m >>= 1) pd += __shfl_xor(pd, m);

  __hip_bfloat162* o1 = (__hip_bfloat162*)(Hb + (size_t)row * DIM);
  __hip_bfloat162* o2 = (__hip_bfloat162*)(Hb + (size_t)(row + N_ROWS) * DIM);
  __hip_bfloat162 t1, t2;
  t1.x = __float2bfloat16(ax * SCALE_SQRT); t1.y = __float2bfloat16(ay * SCALE_SQRT);
  t2.x = __float2bfloat16(bx * SCALE_SQRT); t2.y = __float2bfloat16(by * SCALE_SQRT);
  o1[lane] = t1;
  o2[lane] = t2;

  if (lane == 0) posdot[row] = pd;
}

// ---------------------------------------------------------------------------
// Kernel 2: row sums of exp2(Hs Hs^T) (== exp(2 H H^T)) without materializing.
// Block: 4 waves; each wave owns 64 rows (A resident in VGPR/AGPR, K=128).
// B tiles (64 cols x 128 k) staged via global_load_lds in MFMA fragment order
// so ds_read_b128 is lane-sequential (2-way alias = free).
// Grid (64 row-stripes, 16 col-splits) = 1024 blocks.
// launch_bounds(256,2): 256-reg unified budget. (256,4) = 128-reg cap caused
// a catastrophic scratch spill (R3: WRITE_SIZE 372 MB, MfmaUtil 8.8%) — the
// A fragments live in AGPRs and the total demand is ~140 unified regs.
// Last-finishing block computes the final loss (completion-counter pattern).
// ---------------------------------------------------------------------------
__global__ __launch_bounds__(256, 2) void ntx_main(
    const __hip_bfloat16* __restrict__ Hb, float* __restrict__ rowsum,
    const float* __restrict__ posdot, unsigned* __restrict__ counter,
    float* __restrict__ out) {
  __shared__ short smem[1024 * 8];   // 16 KB: 1024 chunks of 16 B
  const short* H = (const short*)Hb;

  int tid  = threadIdx.x;
  int lane = tid & 63;
  int w    = tid >> 6;
  int q    = lane >> 4;     // k-chunk selector within fragment
  int m    = lane & 15;     // row/col within 16-subtile

  int rowbase = blockIdx.x * 256 + w * 64;
  int colbase = blockIdx.y * COLS_PER_BLOCK;

  // A fragments: 4 row-subtiles x 4 k-steps, resident for the whole kernel.
  short8 a[4][4];
  #pragma unroll
  for (int r = 0; r < 4; ++r)
    #pragma unroll
    for (int s = 0; s < 4; ++s)
      a[r][s] = *(const short8*)(H + (size_t)(rowbase + r * 16 + m) * DIM + s * 32 + q * 8);

  float rowacc[4][4];
  #pragma unroll
  for (int r = 0; r < 4; ++r)
    #pragma unroll
    for (int i = 0; i < 4; ++i) rowacc[r][i] = 0.0f;

  // staging address components (invariant across tiles)
  int s_l15 = tid & 15;            // B row within subtile
  int s_lq  = (tid >> 4) & 3;      // k chunk
  int s_s   = (tid >> 6) & 3;      // k step (== wave id)

  for (int ct = 0; ct < NT; ++ct) {
    int j0 = colbase + ct * CT;
    #pragma unroll
    for (int rr = 0; rr < 4; ++rr) {
      int i = rr * 256 + tid;      // chunk index 0..1023; c = rr
      const short* g = H + (size_t)(j0 + rr * 16 + s_l15) * DIM + s_s * 32 + s_lq * 8;
      async_copy16(g, (void*)&smem[i * 8]);
    }
    __syncthreads();

    #pragma unroll
    for (int c = 0; c < 4; ++c) {
      short8 b[4];
      #pragma unroll
      for (int s = 0; s < 4; ++s)
        b[s] = *(const short8*)&smem[(c * 256 + s * 64 + lane) * 8];
      #pragma unroll
      for (int r = 0; r < 4; ++r) {
        float4v acc = {0.f, 0.f, 0.f, 0.f};
        #pragma unroll
        for (int s = 0; s < 4; ++s)
          acc = __builtin_amdgcn_mfma_f32_16x16x32_bf16(a[r][s], b[s], acc, 0, 0, 0);
        #pragma unroll
        for (int i = 0; i < 4; ++i)
          rowacc[r][i] += __builtin_amdgcn_exp2f(acc[i]);
      }
    }
    __syncthreads();
  }

  // Reduce across the 16 column-lanes holding the same rows, then atomicAdd.
  #pragma unroll
  for (int r = 0; r < 4; ++r)
    #pragma unroll
    for (int i = 0; i < 4; ++i) {
      float v = rowacc[r][i];
      v += __shfl_xor(v, 1);
      v += __shfl_xor(v, 2);
      v += __shfl_xor(v, 4);
      v += __shfl_xor(v, 8);
      rowacc[r][i] = v;
    }
  if (m == 0) {
    #pragma unroll
    for (int r = 0; r < 4; ++r)
      #pragma unroll
      for (int i = 0; i < 4; ++i)
        atomicAdd(&rowsum[rowbase + r * 16 + q * 4 + i], rowacc[r][i]);
  }

  // ---- completion-counter finalize (last block computes the loss) ----
  __shared__ unsigned is_last;
  __threadfence();          // release our rowsum atomics
  __syncthreads();
  if (tid == 0) {
    unsigned old = atomicAdd(counter, 1u);
    is_last = (old == NBLOCKS - 1) ? 1u : 0u;
  }
  __syncthreads();
  if (is_last) {
    __threadfence();        // acquire all blocks' rowsum atomics
    float* smemf = (float*)smem;
    float ld = 0.0f, pp = 0.0f;
    for (int i = tid; i < TWO_N; i += 256) {
      float v = __hip_atomic_load(&rowsum[i], __ATOMIC_RELAXED, __HIP_MEMORY_SCOPE_AGENT);
      ld += __logf(v - EXP_TWO);
    }
    for (int i = tid; i < N_ROWS; i += 256) pp += posdot[i];
    #pragma unroll
    for (int mm = 32; mm; mm >>= 1) {
      ld += __shfl_xor(ld, mm);
      pp += __shfl_xor(pp, mm);
    }
    if (lane == 0) { smemf[w] = ld; smemf[4 + w] = pp; }
    __syncthreads();
    if (tid == 0) {
      float tl = smemf[0] + smemf[1] + smemf[2] + smemf[3];
      float tp = smemf[4] + smemf[5] + smemf[6] + smemf[7];
      *out = (tl - 4.0f * tp) / (float)TWO_N;
    }
  }
}

extern "C" void kernel_launch(void* const* d_in, const int* in_sizes, int n_in,
                              void* d_out, int out_size, void* d_ws, size_t ws_size,
                              hipStream_t stream) {
  const float* h1 = (const float*)d_in[0];
  const float* h2 = (const float*)d_in[1];
  char* ws = (char*)d_ws;

  __hip_bfloat16* Hb = (__hip_bfloat16*)ws;                       // 4 MB
  float* rowsum      = (float*)(ws + 4194304);                    // 64 KB
  float* posdot      = (float*)(ws + 4194304 + 65536);            // 32 KB
  unsigned* counter  = (unsigned*)(ws + 4194304 + 65536 + 32768); // 4 B
  float* out         = (float*)d_out;

  norm_kernel<<<N_ROWS / 4, 256, 0, stream>>>(h1, h2, Hb, posdot, rowsum, counter);
  ntx_main<<<dim3(TWO_N / 256, CSPLIT), 256, 0, stream>>>(Hb, rowsum, posdot, counter, out);
}